// Round 9
// baseline (4491.586 us; speedup 1.0000x reference)
//
#include <hip/hip_runtime.h>

#define TSTEPS 784
#define BATCH  128
#define HID    256
#define WPG    8     // workgroups per group
#define BG     4     // batches per group
#define NGRP   (BATCH / BG)          // 32 groups
#define COLS   32    // hidden cols owned per WG
#define RLOC   128   // local gate rows per WG (4 gates x 32 cols)
typedef unsigned long long u64;
typedef float v4f __attribute__((ext_vector_type(4)));
typedef float v2f __attribute__((ext_vector_type(2)));

// ---------------- prep: permute input (x transposed to [b][t]) ----------------
__global__ void prep_x(const float* __restrict__ in, const int* __restrict__ perm,
                       float* __restrict__ xp) {
    int b = blockIdx.x;
    for (int t = threadIdx.x; t < TSTEPS; t += blockDim.x)
        xp[b * TSTEPS + t] = in[b * TSTEPS + perm[t]];
}

// gslots[par][b][gate][k]: hi32 = tag (1..784), lo32 = activated-gate f32 bits.
// tag 0 = never-written (t=0 staging doesn't poll).
__global__ void prep_slots(u64* __restrict__ gslots) {
    int i = blockIdx.x * blockDim.x + threadIdx.x;
    if (i < 2 * BATCH * 4 * HID) gslots[i] = 0ull;
}

// packed 2-wide f32 fma: acc += a*b
#define PK_FMA(acc, a, b) \
    asm("v_pk_fma_f32 %0, %1, %2, %0" : "+v"(acc) : "v"(a), "v"(b))

// ---------------- main persistent LSTM kernel ----------------
// grid 256 x 1024. group g = blockIdx&31 owns batches [4g,4g+4).
// WG wgi = blockIdx>>5 owns cols [32wgi,32wgi+32) x 4 gates (publishes their
// ACTIVATED gates). Every WG replicates the c-state: thread (pb=tid>>8,
// pk=tid&255) keeps c[B0+pb][pk] in one VGPR, stages h = o*tanh(c) itself.
// Exchange = activated gates (tagged u64), so the producer's post-reduce tail
// is just act+store; the c/h math runs fully parallel in the staging phase.
// One barrier per step: h_lds is double-buffered (wave skew <= 1 phase).
// Dot: r = tid>>3 local gate-row (gate=r>>5, col=r&31), s = tid&7 k-slice of
// 32; 32 weights/thread pinned in VGPRs, rotate-stored -> conflict-free
// broadcast ds_read_b128; v_pk_fma_f32 (proven -90us of VALU time in r8).
__global__ __launch_bounds__(1024, 4) void lstm_kernel(
    const float* __restrict__ Whh, const float* __restrict__ Wih,
    const float* __restrict__ bih, const float* __restrict__ bhh,
    const float* __restrict__ xp, u64* __restrict__ gslots,
    float* __restrict__ hout)
{
    __shared__ float h_lds[2][BG * HID];         // 8 KB double-buffered h_t
    __shared__ float x_lds[BG * TSTEPS];         // 12.25 KB
    __shared__ float bias_lds[RLOC];
    __shared__ float win_lds[RLOC];

    const int tid = threadIdx.x;
    const int g       = blockIdx.x & 31;
    const int wgi     = blockIdx.x >> 5;
    const int B0      = g * BG;
    const int colbase = wgi * COLS;

    const int r = tid >> 3;                  // local gate-row 0..127
    const int s = tid & 7;                   // k-slice
    const int gate = r >> 5;                 // wave-uniform
    const int R = gate * 256 + colbase + (r & 31);   // global gate row

    // ---- one-time loads; rotate-store: reg d holds quad index (d+s)&7 ----
    v4f w0, w1, w2, w3, w4, w5, w6, w7;
    {
        const v4f* wp = (const v4f*)(Whh + R * HID + s * 32);
        w0 = wp[(0 + s) & 7]; w1 = wp[(1 + s) & 7];
        w2 = wp[(2 + s) & 7]; w3 = wp[(3 + s) & 7];
        w4 = wp[(4 + s) & 7]; w5 = wp[(5 + s) & 7];
        w6 = wp[(6 + s) & 7]; w7 = wp[(7 + s) & 7];
    }
    #define KEEPV(V) asm volatile("" : "+v"(V))
    KEEPV(w0); KEEPV(w1); KEEPV(w2); KEEPV(w3);
    KEEPV(w4); KEEPV(w5); KEEPV(w6); KEEPV(w7);
    #undef KEEPV

    if (tid < RLOC) {
        int gr = (tid >> 5) * 256 + colbase + (tid & 31);
        bias_lds[tid] = bih[gr] + bhh[gr];
        win_lds[tid]  = Wih[gr];
    }
    #pragma unroll
    for (int b = 0; b < BG; ++b)
        if (tid < TSTEPS) x_lds[b * TSTEPS + tid] = xp[(B0 + b) * TSTEPS + tid];
    __syncthreads();

    // staging identity: this thread owns (pb, pk); c[B0+pb][pk] in a VGPR
    const int pb = tid >> 8, pk = tid & 255;
    u64* const sbase0 = gslots + (u64)((0 * BATCH + B0 + pb) * 4) * HID + pk;
    u64* const sbase1 = gslots + (u64)((1 * BATCH + B0 + pb) * 4) * HID + pk;
    float c_reg = 0.f;

    for (int t = 0; t <= TSTEPS; ++t) {
        // ---- stage h_t: poll 4 tagged gate slots, update c, compute h ----
        float hval;
        if (t == 0) {
            hval = 0.f;                        // h0 = c0 = 0
        } else {
            u64* sp = (t & 1) ? sbase1 : sbase0;
            u64 vi, vf, vg, vo;
            const unsigned tt = (unsigned)t;
            for (;;) {
                vi = __hip_atomic_load(sp,           __ATOMIC_RELAXED, __HIP_MEMORY_SCOPE_AGENT);
                vf = __hip_atomic_load(sp + HID,     __ATOMIC_RELAXED, __HIP_MEMORY_SCOPE_AGENT);
                vg = __hip_atomic_load(sp + 2 * HID, __ATOMIC_RELAXED, __HIP_MEMORY_SCOPE_AGENT);
                vo = __hip_atomic_load(sp + 3 * HID, __ATOMIC_RELAXED, __HIP_MEMORY_SCOPE_AGENT);
                if ((unsigned)(vi >> 32) == tt && (unsigned)(vf >> 32) == tt &&
                    (unsigned)(vg >> 32) == tt && (unsigned)(vo >> 32) == tt) break;
            }
            float iv = __uint_as_float((unsigned)vi);
            float fv = __uint_as_float((unsigned)vf);
            float gv = __uint_as_float((unsigned)vg);
            float ov = __uint_as_float((unsigned)vo);
            c_reg = fmaf(fv, c_reg, iv * gv);
            float tc = 2.f / (1.f + __expf(-2.f * c_reg)) - 1.f;
            hval = ov * tc;
        }
        h_lds[t & 1][tid] = hval;
        if (t == TSTEPS) {
            if (wgi == 0) hout[(B0 + pb) * HID + pk] = hval;  // replicas identical
            break;
        }
        __syncthreads();   // single barrier/step: next staging targets buf^1

        // ---- dot: pk_fma, weights in VGPRs, rotated broadcast b128 h reads ----
        v2f acc0 = {0.f, 0.f}, acc1 = {0.f, 0.f}, acc2 = {0.f, 0.f}, acc3 = {0.f, 0.f};
        const float* hbase = h_lds[t & 1] + s * 32;
        #define DOT_STEP(d, wd)                                               \
        {                                                                     \
            int off = (((d) + s) & 7) * 4;                                    \
            v4f hq0 = *(const v4f*)(hbase + off);                             \
            v4f hq1 = *(const v4f*)(hbase + 256 + off);                       \
            v4f hq2 = *(const v4f*)(hbase + 512 + off);                       \
            v4f hq3 = *(const v4f*)(hbase + 768 + off);                       \
            v2f wlo = __builtin_shufflevector(wd, wd, 0, 1);                  \
            v2f whi = __builtin_shufflevector(wd, wd, 2, 3);                  \
            PK_FMA(acc0, wlo, __builtin_shufflevector(hq0, hq0, 0, 1));       \
            PK_FMA(acc0, whi, __builtin_shufflevector(hq0, hq0, 2, 3));       \
            PK_FMA(acc1, wlo, __builtin_shufflevector(hq1, hq1, 0, 1));       \
            PK_FMA(acc1, whi, __builtin_shufflevector(hq1, hq1, 2, 3));       \
            PK_FMA(acc2, wlo, __builtin_shufflevector(hq2, hq2, 0, 1));       \
            PK_FMA(acc2, whi, __builtin_shufflevector(hq2, hq2, 2, 3));       \
            PK_FMA(acc3, wlo, __builtin_shufflevector(hq3, hq3, 0, 1));       \
            PK_FMA(acc3, whi, __builtin_shufflevector(hq3, hq3, 2, 3));       \
        }
        DOT_STEP(0, w0) DOT_STEP(1, w1) DOT_STEP(2, w2) DOT_STEP(3, w3)
        DOT_STEP(4, w4) DOT_STEP(5, w5) DOT_STEP(6, w6) DOT_STEP(7, w7)
        #undef DOT_STEP

        float a0 = acc0.x + acc0.y;
        float a1 = acc1.x + acc1.y;
        float a2 = acc2.x + acc2.y;
        float a3 = acc3.x + acc3.y;

        // ---- k-reduce across the 8 slice-lanes (in-wave butterfly) ----
        #pragma unroll
        for (int m = 1; m < 8; m <<= 1) {
            a0 += __shfl_xor(a0, m, 64);
            a1 += __shfl_xor(a1, m, 64);
            a2 += __shfl_xor(a2, m, 64);
            a3 += __shfl_xor(a3, m, 64);
        }

        // ---- lane s<4 finishes batch b=s: bias + w_in*x, activate, PUBLISH ----
        if (s < BG) {
            float sum = (s == 0) ? a0 : (s == 1) ? a1 : (s == 2) ? a2 : a3;
            float xv = x_lds[s * TSTEPS + t];
            float full = fmaf(win_lds[r], xv, sum + bias_lds[r]);
            float pre = (gate == 2) ? 2.f * full : full;       // tanh = 2sig(2x)-1
            float rec = 1.f / (1.f + __expf(-pre));
            float act = (gate == 2) ? fmaf(2.f, rec, -1.f) : rec;
            u64 val = ((u64)(unsigned)(t + 1) << 32) | (u64)__float_as_uint(act);
            u64* dp = gslots + (u64)((((t + 1) & 1) * BATCH + B0 + s) * 4 + gate) * HID
                             + colbase + (r & 31);
            __hip_atomic_store(dp, val, __ATOMIC_RELAXED, __HIP_MEMORY_SCOPE_AGENT);
        }
        // no second barrier: staging of t+1 writes h_lds[(t+1)&1] (other buffer)
        // and waves can skew at most one phase before the next barrier.
    }
}

// ---------------- final linear: out = h_784 @ lin_W.T + lin_b ----------------
__global__ void out_kernel(const float* __restrict__ hout, const float* __restrict__ linW,
                           const float* __restrict__ linb, float* __restrict__ out) {
    __shared__ float hl[HID];
    int b = blockIdx.x;
    for (int k = threadIdx.x; k < HID; k += blockDim.x) hl[k] = hout[b * HID + k];
    __syncthreads();
    if (threadIdx.x < 10) {
        int n = threadIdx.x;
        float acc = linb[n];
        for (int k = 0; k < HID; ++k) acc = fmaf(hl[k], linW[n * HID + k], acc);
        out[b * 10 + n] = acc;
    }
}

extern "C" void kernel_launch(void* const* d_in, const int* in_sizes, int n_in,
                              void* d_out, int out_size, void* d_ws, size_t ws_size,
                              hipStream_t stream) {
    const float* inputs = (const float*)d_in[0];
    const int*   perm   = (const int*)d_in[1];
    const float* Wih    = (const float*)d_in[2];
    const float* Whh    = (const float*)d_in[3];
    const float* bih    = (const float*)d_in[4];
    const float* bhh    = (const float*)d_in[5];
    const float* linW   = (const float*)d_in[6];
    const float* linb   = (const float*)d_in[7];
    float* out = (float*)d_out;

    // d_ws: gslots[2][128][4][256] u64 (2MB) | xp[128][784] f32 (401KB) | hout (128KB)
    u64*   gslots = (u64*)d_ws;
    float* xp     = (float*)(gslots + 2 * BATCH * 4 * HID);
    float* hout   = xp + BATCH * TSTEPS;

    prep_x<<<BATCH, 256, 0, stream>>>(inputs, perm, xp);
    prep_slots<<<(2 * BATCH * 4 * HID + 255) / 256, 256, 0, stream>>>(gslots);
    lstm_kernel<<<NGRP * WPG, 1024, 0, stream>>>(Whh, Wih, bih, bhh, xp, gslots, hout);
    out_kernel<<<BATCH, 64, 0, stream>>>(hout, linW, linb, out);
}

// Round 10
// 2345.986 us; speedup vs baseline: 1.9146x; 1.9146x over previous
//
#include <hip/hip_runtime.h>

#define TSTEPS 784
#define BATCH  128
#define HID    256
#define WPG    8     // workgroups per group
#define BG     4     // batches per group
#define NGRP   (BATCH / BG)          // 32 groups
#define COLS   32    // hidden cols owned per WG
#define RLOC   128   // local gate rows per WG (4 gates x 32 cols)
#define NPOLL  448   // pollers: 4 batches x 112 partner x4-units (2 slots each)
#define MAXFAST 512  // fast-poll iterations before sticky per-slot fallback
typedef unsigned long long u64;
typedef float v4f __attribute__((ext_vector_type(4)));
typedef float v2f __attribute__((ext_vector_type(2)));
typedef unsigned int v4u __attribute__((ext_vector_type(4)));

// ---------------- prep: permute input (x transposed to [b][t]) ----------------
__global__ void prep_x(const float* __restrict__ in, const int* __restrict__ perm,
                       float* __restrict__ xp) {
    int b = blockIdx.x;
    for (int t = threadIdx.x; t < TSTEPS; t += blockDim.x)
        xp[b * TSTEPS + t] = in[b * TSTEPS + perm[t]];
}

// slots[parity][b][k]: hi32 = tag, lo32 = f32 bits. parity0: tag0/val0 = 0ull.
__global__ void prep_slots(u64* __restrict__ slots) {
    int i = blockIdx.x * blockDim.x + threadIdx.x;
    if (i < BATCH * HID)          slots[i] = 0ull;
    else if (i < 2 * BATCH * HID) slots[i] = 0xFFFFFFFF00000000ull;
}

// packed 2-wide f32 fma: acc += a*b
#define PK_FMA(acc, a, b) \
    asm("v_pk_fma_f32 %0, %1, %2, %0" : "+v"(acc) : "v"(a), "v"(b))

// ---------------- main persistent LSTM kernel ----------------
// grid 256 x 1024. group g = blockIdx&31 owns batches [4g,4g+4).
// WG wgi = blockIdx>>5 owns cols [32wgi,32wgi+32).
// Exchange (r4-proven tagged u64 slots) with two traffic cuts:
//  (a) own 128 h values go straight to double-buffered h_lds (no self-poll);
//  (b) partner slots polled PAIRWISE: 448 pollers, one global_load_dwordx4
//      (sc0 sc1 = LLC-coherent, same path the 8B agent atomics use) checking
//      two tags per iteration. Each 8B half is a self-validating {tag,val},
//      so cross-half tearing is benign; a watchdog falls back (sticky) to
//      per-slot atomic polls, so progress never depends on cache behavior.
// Dot: r = tid>>3 local gate-row (gate=r>>5, col=r&31), s = tid&7 k-slice of
// 32; weights pinned in VGPRs rotate-stored (conflict-free broadcast b128);
// v_pk_fma_f32 (r8: -90us VALU). Epilogue: r4's gate_lds form (proven).
__global__ __launch_bounds__(1024, 4) void lstm_kernel(
    const float* __restrict__ Whh, const float* __restrict__ Wih,
    const float* __restrict__ bih, const float* __restrict__ bhh,
    const float* __restrict__ xp, u64* __restrict__ slots)
{
    __shared__ float h_lds[2][BG * HID];         // 8 KB double-buffered h_t
    __shared__ float gate_lds[BG * 132];         // activated gates, padded
    __shared__ float x_lds[BG * TSTEPS];         // 12.25 KB
    __shared__ float c_lds[BG * COLS];
    __shared__ float bias_lds[RLOC];
    __shared__ float win_lds[RLOC];

    const int tid = threadIdx.x;
    const int g       = blockIdx.x & 31;
    const int wgi     = blockIdx.x >> 5;
    const int B0      = g * BG;
    const int colbase = wgi * COLS;

    const int r = tid >> 3;                  // local gate-row 0..127
    const int s = tid & 7;                   // k-slice
    const int gate = r >> 5;                 // wave-uniform
    const int R = gate * 256 + colbase + (r & 31);   // global gate row

    // ---- one-time loads; rotate-store: reg d holds quad index (d+s)&7 ----
    v4f w0, w1, w2, w3, w4, w5, w6, w7;
    {
        const v4f* wp = (const v4f*)(Whh + R * HID + s * 32);
        w0 = wp[(0 + s) & 7]; w1 = wp[(1 + s) & 7];
        w2 = wp[(2 + s) & 7]; w3 = wp[(3 + s) & 7];
        w4 = wp[(4 + s) & 7]; w5 = wp[(5 + s) & 7];
        w6 = wp[(6 + s) & 7]; w7 = wp[(7 + s) & 7];
    }
    #define KEEPV(V) asm volatile("" : "+v"(V))
    KEEPV(w0); KEEPV(w1); KEEPV(w2); KEEPV(w3);
    KEEPV(w4); KEEPV(w5); KEEPV(w6); KEEPV(w7);
    #undef KEEPV

    if (tid < RLOC) {
        int gr = (tid >> 5) * 256 + colbase + (tid & 31);
        bias_lds[tid] = bih[gr] + bhh[gr];
        win_lds[tid]  = Wih[gr];
    }
    #pragma unroll
    for (int b = 0; b < BG; ++b)
        if (tid < TSTEPS) x_lds[b * TSTEPS + tid] = xp[(B0 + b) * TSTEPS + tid];
    if (tid < BG * COLS) c_lds[tid] = 0.f;
    h_lds[0][tid] = 0.f;                       // h_0 = 0 (no polls at t=0)

    // ---- poller identity: pairs of partner slots (skip own 16 units/batch) ----
    int pb_ = 0, uu_ = 0;
    u64* ppair0 = slots;
    u64* ppair1 = slots;
    if (tid < NPOLL) {
        int b = tid / 112, u = tid - 112 * b;
        int uu = u + (u >= (colbase >> 1) ? 16 : 0);   // skip own unit range
        pb_ = b; uu_ = uu;
        ppair0 = slots + (B0 + b) * HID + 2 * uu;               // parity 0
        ppair1 = slots + BATCH * HID + (B0 + b) * HID + 2 * uu; // parity 1
    }
    bool fast_ok = true;
    __syncthreads();

    for (int t = 0; t < TSTEPS; ++t) {
        const int cur = t & 1;
        // ---- stage partner h_t: 16B tagged-pair polls ----
        if (t > 0 && tid < NPOLL) {
            u64* sp = cur ? ppair1 : ppair0;
            const unsigned tt = (unsigned)t;
            v4u v;
            if (fast_ok) {
                int it = 0;
                for (;;) {
                    asm volatile("global_load_dwordx4 %0, %1, off sc0 sc1\n\t"
                                 "s_waitcnt vmcnt(0)"
                                 : "=v"(v) : "v"(sp) : "memory");
                    if (v.y == tt && v.w == tt) break;
                    if (++it >= MAXFAST) { fast_ok = false; break; }
                }
            }
            if (!fast_ok) {   // sticky safe path: per-slot agent atomics
                u64 a, b2;
                do { a = __hip_atomic_load(sp, __ATOMIC_RELAXED, __HIP_MEMORY_SCOPE_AGENT);
                } while ((unsigned)(a >> 32) != tt);
                do { b2 = __hip_atomic_load(sp + 1, __ATOMIC_RELAXED, __HIP_MEMORY_SCOPE_AGENT);
                } while ((unsigned)(b2 >> 32) != tt);
                v.x = (unsigned)a; v.z = (unsigned)b2;
            }
            float2 hv;
            hv.x = __uint_as_float(v.x);
            hv.y = __uint_as_float(v.z);
            *(float2*)&h_lds[cur][pb_ * HID + 2 * uu_] = hv;
        }
        __syncthreads();

        // ---- dot: pk_fma, weights in VGPRs, rotated broadcast b128 h reads ----
        v2f acc0 = {0.f, 0.f}, acc1 = {0.f, 0.f}, acc2 = {0.f, 0.f}, acc3 = {0.f, 0.f};
        const float* hbase = h_lds[cur] + s * 32;
        #define DOT_STEP(d, wd)                                               \
        {                                                                     \
            int off = (((d) + s) & 7) * 4;                                    \
            v4f hq0 = *(const v4f*)(hbase + off);                             \
            v4f hq1 = *(const v4f*)(hbase + 256 + off);                       \
            v4f hq2 = *(const v4f*)(hbase + 512 + off);                       \
            v4f hq3 = *(const v4f*)(hbase + 768 + off);                       \
            v2f wlo = __builtin_shufflevector(wd, wd, 0, 1);                  \
            v2f whi = __builtin_shufflevector(wd, wd, 2, 3);                  \
            PK_FMA(acc0, wlo, __builtin_shufflevector(hq0, hq0, 0, 1));       \
            PK_FMA(acc0, whi, __builtin_shufflevector(hq0, hq0, 2, 3));       \
            PK_FMA(acc1, wlo, __builtin_shufflevector(hq1, hq1, 0, 1));       \
            PK_FMA(acc1, whi, __builtin_shufflevector(hq1, hq1, 2, 3));       \
            PK_FMA(acc2, wlo, __builtin_shufflevector(hq2, hq2, 0, 1));       \
            PK_FMA(acc2, whi, __builtin_shufflevector(hq2, hq2, 2, 3));       \
            PK_FMA(acc3, wlo, __builtin_shufflevector(hq3, hq3, 0, 1));       \
            PK_FMA(acc3, whi, __builtin_shufflevector(hq3, hq3, 2, 3));       \
        }
        DOT_STEP(0, w0) DOT_STEP(1, w1) DOT_STEP(2, w2) DOT_STEP(3, w3)
        DOT_STEP(4, w4) DOT_STEP(5, w5) DOT_STEP(6, w6) DOT_STEP(7, w7)
        #undef DOT_STEP

        float a0 = acc0.x + acc0.y;
        float a1 = acc1.x + acc1.y;
        float a2 = acc2.x + acc2.y;
        float a3 = acc3.x + acc3.y;

        // ---- k-reduce across the 8 slice-lanes (in-wave butterfly) ----
        #pragma unroll
        for (int m = 1; m < 8; m <<= 1) {
            a0 += __shfl_xor(a0, m, 64);
            a1 += __shfl_xor(a1, m, 64);
            a2 += __shfl_xor(a2, m, 64);
            a3 += __shfl_xor(a3, m, 64);
        }
        // lane s finishes batch s: bias + w_in*x, activate (gate wave-uniform)
        if (s < BG) {
            float sum = (s == 0) ? a0 : (s == 1) ? a1 : (s == 2) ? a2 : a3;
            float xv = x_lds[s * TSTEPS + t];
            float full = fmaf(win_lds[r], xv, sum + bias_lds[r]);
            float pre = (gate == 2) ? 2.f * full : full;     // tanh = 2sig(2x)-1
            float rec = 1.f / (1.f + __expf(-pre));
            float act = (gate == 2) ? fmaf(2.f, rec, -1.f) : rec;
            gate_lds[s * 132 + r] = act;
        }
        __syncthreads();

        // ---- c/h update (128 threads): LDS own-half + publish tagged h ----
        if (tid < BG * COLS) {
            int b = tid >> 5, j = tid & 31;
            float iv = gate_lds[b * 132 + j];
            float fv = gate_lds[b * 132 + 32 + j];
            float gv = gate_lds[b * 132 + 64 + j];
            float ov = gate_lds[b * 132 + 96 + j];
            float cn = fmaf(fv, c_lds[tid], iv * gv);
            c_lds[tid] = cn;
            float tc = 2.f / (1.f + __expf(-2.f * cn)) - 1.f;
            float hn = ov * tc;
            h_lds[cur ^ 1][b * HID + colbase + j] = hn;   // own half: no self-poll
            u64 val = ((u64)(unsigned)(t + 1) << 32) | (u64)__float_as_uint(hn);
            u64* dp = slots + ((t + 1) & 1) * (BATCH * HID)
                            + (B0 + b) * HID + colbase + j;
            __hip_atomic_store(dp, val, __ATOMIC_RELAXED, __HIP_MEMORY_SCOPE_AGENT);
        }
        // no trailing barrier: pollers of step t+1 write h_lds[cur^1] partner
        // range (disjoint from update's own range); the next stage-barrier
        // orders both before the dot. h_lds[cur] re-write happens at t+2,
        // two barriers after all dot(t) reads.
    }
}

// ---------------- final linear: out = h_784 @ lin_W.T + lin_b ----------------
__global__ void out_kernel(const u64* __restrict__ slots, const float* __restrict__ linW,
                           const float* __restrict__ linb, float* __restrict__ out) {
    __shared__ float hl[HID];
    int b = blockIdx.x;
    // T=784 even -> final h is in parity-0 slots, low 32 bits
    for (int k = threadIdx.x; k < HID; k += blockDim.x)
        hl[k] = __uint_as_float((unsigned)slots[b * HID + k]);
    __syncthreads();
    if (threadIdx.x < 10) {
        int n = threadIdx.x;
        float acc = linb[n];
        for (int k = 0; k < HID; ++k) acc = fmaf(hl[k], linW[n * HID + k], acc);
        out[b * 10 + n] = acc;
    }
}

extern "C" void kernel_launch(void* const* d_in, const int* in_sizes, int n_in,
                              void* d_out, int out_size, void* d_ws, size_t ws_size,
                              hipStream_t stream) {
    const float* inputs = (const float*)d_in[0];
    const int*   perm   = (const int*)d_in[1];
    const float* Wih    = (const float*)d_in[2];
    const float* Whh    = (const float*)d_in[3];
    const float* bih    = (const float*)d_in[4];
    const float* bhh    = (const float*)d_in[5];
    const float* linW   = (const float*)d_in[6];
    const float* linb   = (const float*)d_in[7];
    float* out = (float*)d_out;

    // d_ws layout: slots[2][128][256] u64 (512KB) | xp[128][784] f32 (401KB)
    u64*   slots = (u64*)d_ws;
    float* xp    = (float*)(slots + 2 * BATCH * HID);

    prep_x<<<BATCH, 256, 0, stream>>>(inputs, perm, xp);
    prep_slots<<<(2 * BATCH * HID + 255) / 256, 256, 0, stream>>>(slots);
    lstm_kernel<<<NGRP * WPG, 1024, 0, stream>>>(Whh, Wih, bih, bhh, xp, slots);
    out_kernel<<<BATCH, 64, 0, stream>>>(slots, linW, linb, out);
}